// Round 23
// baseline (314.252 us; speedup 1.0000x reference)
//
#include <hip/hip_runtime.h>
#include <stdint.h>

#define DEVI __device__ __forceinline__

typedef __attribute__((ext_vector_type(8))) uint16_t u16x8;
typedef __attribute__((ext_vector_type(4))) uint16_t u16x4v;
typedef __attribute__((ext_vector_type(4))) uint32_t u32x4;
typedef __attribute__((ext_vector_type(8))) __bf16 bf16x8;
typedef __attribute__((ext_vector_type(4))) float f32x4;
typedef __attribute__((ext_vector_type(16))) float f32x16;

DEVI uint16_t f2bf(float x) {
  union { float f; uint32_t u; } v; v.f = x;
  return (uint16_t)((v.u + 0x7fffu + ((v.u >> 16) & 1u)) >> 16);
}

DEVI uint16_t f2bfn(float f) {
  __bf16 h = (__bf16)f;
  return __builtin_bit_cast(uint16_t, h);
}

DEVI f32x4 mfma16(u16x8 a, u16x8 b, f32x4 c) {
  return __builtin_amdgcn_mfma_f32_16x16x32_bf16(
      __builtin_bit_cast(bf16x8, a), __builtin_bit_cast(bf16x8, b), c, 0, 0, 0);
}

DEVI f32x16 mfma32(u16x8 a, u16x8 b, f32x16 c) {
  return __builtin_amdgcn_mfma_f32_32x32x16_bf16(
      __builtin_bit_cast(bf16x8, a), __builtin_bit_cast(bf16x8, b), c, 0, 0, 0);
}

DEVI void async16(void* lds, const void* g) {
  __builtin_amdgcn_global_load_lds(
      (const __attribute__((address_space(1))) uint32_t*)g,
      (__attribute__((address_space(3))) uint32_t*)lds, 16, 0, 0);
}

// 1/sqrt(128) * log2(e): softmax computed in exp2 domain, scale folded into Q.
#define QSC 0.12751742925f

// ---------------- elementwise f32 -> bf16 ----------------
__global__ void cvt_f32_bf16(const float* __restrict__ in, uint16_t* __restrict__ out, int n4) {
  int i = blockIdx.x * blockDim.x + threadIdx.x;
  const int st = gridDim.x * blockDim.x;
  for (; i < n4; i += st) {
    float4 v = ((const float4*)in)[i];
    u16x4v o;
    o[0] = f2bf(v.x); o[1] = f2bf(v.y); o[2] = f2bf(v.z); o[3] = f2bf(v.w);
    ((u16x4v*)out)[i] = o;
  }
}

// ------------- transpose + convert: f32 [K][N] -> bf16 [N][K] -------------
__global__ void transp_cvt(const float* __restrict__ in, uint16_t* __restrict__ out,
                           int K, int N) {
  __shared__ float Ws[64][65];
  const int n0 = blockIdx.x * 64, k0 = blockIdx.y * 64;
  const int t = threadIdx.x;
  const int r = t >> 4, c = (t & 15) << 2;
#pragma unroll
  for (int it = 0; it < 4; ++it) {
    float4 v = *(const float4*)&in[(size_t)(k0 + it * 16 + r) * N + n0 + c];
    Ws[it * 16 + r][c] = v.x; Ws[it * 16 + r][c + 1] = v.y;
    Ws[it * 16 + r][c + 2] = v.z; Ws[it * 16 + r][c + 3] = v.w;
  }
  __syncthreads();
#pragma unroll
  for (int it = 0; it < 4; ++it) {
    const int rr = it * 16 + r;   // n index in tile
    const int cc = c;             // k index in tile
    ushort4 o;
    o.x = f2bf(Ws[cc][rr]);     o.y = f2bf(Ws[cc + 1][rr]);
    o.z = f2bf(Ws[cc + 2][rr]); o.w = f2bf(Ws[cc + 3][rr]);
    *(ushort4*)&out[(size_t)(n0 + rr) * K + k0 + cc] = o;
  }
}

// ------ qkv GEMM: 256x192 tile, SINGLE-phase x 48-MFMA (round-21) ------
// ROUND 23: COLUMN-MAJOR block decode (brow = bid%nbm, bcol = bid/nbm).
// After XCD swizzle, same-XCD consecutive blocks (+8 apart in original id)
// now share the SAME 768 KB B panel for runs of 4 (B stays L2-resident;
// only the 1 MB A panels stream) — previously they swept all 16 B panels
// through each 4 MB XCD L2 per A panel.
__global__ __launch_bounds__(512, 1)
void gemm_qkv(const uint16_t* __restrict__ A, const uint16_t* __restrict__ Bt,
              const float* __restrict__ bias,
              uint16_t* __restrict__ q, uint16_t* __restrict__ kk, uint16_t* __restrict__ vt,
              int M, int N, int K) {
  constexpr int BK = 64;
  __shared__ uint16_t As[2][256 * BK];   // 64 KB
  __shared__ uint16_t Bs[2][192 * BK];   // 48 KB
  int bid = (int)blockIdx.x;
  const int q8 = (int)gridDim.x >> 3;
  bid = (bid & 7) * q8 + (bid >> 3);
  const int nbm = M >> 8;                         // 32 row-blocks
  const int brow = (bid % nbm) << 8;
  const int bcol = (bid / nbm) * 192;
  const int t = threadIdx.x;
  const int wid = t >> 6, lane = t & 63;
  const int wm = wid >> 1, wn = wid & 1;          // 4 x 2 wave grid (64 x 96 per wave)
  const int lr = lane & 15, g = lane >> 4, l7 = lr & 7;

  const int logch = (((t & 7) ^ ((t >> 3) & 7)) << 3);
  const uint16_t* Asrc = A + (size_t)(brow + (t >> 3)) * K + logch;
  const uint16_t* Bsrc = Bt + (size_t)(bcol + (t >> 3)) * K + logch;
  const size_t skip64 = (size_t)64 * K;
  const int dt = t * 8;

  auto stageA = [&](int buf, int k0) {
#pragma unroll
    for (int l = 0; l < 4; ++l)
      async16(&As[buf][l * 4096 + dt], Asrc + (size_t)l * skip64 + k0);
  };
  auto stageB = [&](int buf, int k0) {
#pragma unroll
    for (int l = 0; l < 3; ++l)
      async16(&Bs[buf][l * 4096 + dt], Bsrc + (size_t)l * skip64 + k0);
  };

  f32x4 acc[4][6];
#pragma unroll
  for (int i = 0; i < 4; ++i)
#pragma unroll
    for (int j = 0; j < 6; ++j) acc[i][j] = f32x4{0.f, 0.f, 0.f, 0.f};

  const int nt = K / BK;
  stageA(0, 0); stageB(0, 0);
  if (nt > 1) { stageA(1, BK); stageB(1, BK); }
  asm volatile("s_waitcnt vmcnt(0)" ::: "memory");
  __builtin_amdgcn_s_barrier();

  for (int tt = 0; tt < nt; ++tt) {
    const int buf = tt & 1;
    u16x8 bfr[6][2], af[4][2];
#pragma unroll
    for (int j = 0; j < 6; ++j) {
      const int brw = wn * 96 + j * 16 + lr;
#pragma unroll
      for (int s = 0; s < 2; ++s)
        bfr[j][s] = *(const u16x8*)&Bs[buf][brw * 64 + ((((s << 2) + g) ^ l7) << 3)];
    }
#pragma unroll
    for (int ii = 0; ii < 4; ++ii) {
      const int arow = wm * 64 + ii * 16 + lr;
#pragma unroll
      for (int s = 0; s < 2; ++s)
        af[ii][s] = *(const u16x8*)&As[buf][arow * 64 + ((((s << 2) + g) ^ l7) << 3)];
    }
    asm volatile("s_waitcnt lgkmcnt(0)" ::: "memory");
    __builtin_amdgcn_sched_barrier(0);
    __builtin_amdgcn_s_barrier();          // all waves' reads of buf complete
    if (tt + 2 < nt) {
      stageA(buf, (tt + 2) * BK);          // buf is dead; reuse for t+2
      stageB(buf, (tt + 2) * BK);
      asm volatile("s_waitcnt vmcnt(7)" ::: "memory");  // t+1 proven landed
    } else {
      asm volatile("s_waitcnt vmcnt(0)" ::: "memory");
    }
    __builtin_amdgcn_s_setprio(1);
#pragma unroll
    for (int ii = 0; ii < 4; ++ii)
#pragma unroll
      for (int j = 0; j < 6; ++j)
#pragma unroll
        for (int s = 0; s < 2; ++s)
          acc[ii][j] = mfma16(af[ii][s], bfr[j][s], acc[ii][j]);
    __builtin_amdgcn_s_setprio(0);
    __builtin_amdgcn_s_barrier();          // publish vmcnt guarantee
  }

#pragma unroll
  for (int i = 0; i < 4; ++i) {
#pragma unroll
    for (int j = 0; j < 6; ++j) {
      const int col = bcol + wn * 96 + j * 16 + lr;
      const float bb = bias[col];
      const int rowb = brow + wm * 64 + i * 16 + (g << 2);
      const int b_ = rowb >> 11, ttb = rowb & 2047;   // r-span stays in one seq
      const int d = col & 127;
      float vals[4];
#pragma unroll
      for (int r = 0; r < 4; ++r) vals[r] = acc[i][j][r] + bb;
      if (col < 2048) {
        const int hh = col >> 7;
#pragma unroll
        for (int r = 0; r < 4; ++r)
          q[((size_t)((b_ * 16 + hh) * 2048 + ttb + r) << 7) + d] = f2bf(vals[r] * QSC);
      } else if (col < 2560) {
        const int hh = (col - 2048) >> 7;
#pragma unroll
        for (int r = 0; r < 4; ++r)
          kk[((size_t)((b_ * 4 + hh) * 2048 + ttb + r) << 7) + d] = f2bf(vals[r]);
      } else {
        const int hh = (col - 2560) >> 7;
        u16x4v pk;
#pragma unroll
        for (int r = 0; r < 4; ++r) pk[r] = f2bf(vals[r]);
        *(u16x4v*)&vt[(((size_t)((b_ * 4 + hh) * 128 + d)) << 11) + ttb] = pk;
      }
    }
  }
}

// ------ proj GEMM: 256x256, 2-phase x 32-MFMA (round-20, verified) ------
__global__ __launch_bounds__(512, 1)
void gemm_proj(const uint16_t* __restrict__ A, const uint16_t* __restrict__ Bt,
               const float* __restrict__ bias, float* __restrict__ outF,
               int M, int N, int K) {
  constexpr int BK = 64;
  __shared__ uint16_t As[2][256 * BK];   // 64 KB
  __shared__ uint16_t Bs[2][256 * BK];   // 64 KB
  int bid = (int)blockIdx.x;
  const int q8 = (int)gridDim.x >> 3;
  bid = (bid & 7) * q8 + (bid >> 3);
  const int nbn = N >> 8;
  const int brow = (bid / nbn) << 8;
  const int bcol = (bid % nbn) << 8;
  const int t = threadIdx.x;
  const int wid = t >> 6, lane = t & 63;
  const int wm = wid >> 2, wn = wid & 3;          // 2 x 4 wave grid
  const int lr = lane & 15, g = lane >> 4;
  const int l7 = lr & 7;

  const int sr0 = t >> 3;
  const int logch = (((t & 7) ^ ((t >> 3) & 7)) << 3);
  const uint16_t* Asrc0 = A + (size_t)(brow + sr0) * K + logch;
  const uint16_t* Asrc1 = A + (size_t)(brow + 64 + sr0) * K + logch;
  const uint16_t* Bsrc0 = Bt + (size_t)(bcol + sr0) * K + logch;
  const uint16_t* Bsrc1 = Bt + (size_t)(bcol + 64 + sr0) * K + logch;
  const size_t hskip = (size_t)128 * K;
  const int d0 = t * 8, d1 = 4096 + t * 8;

  auto stageA = [&](int buf, int k0) {
    async16(&As[buf][d0], Asrc0 + k0);
    async16(&As[buf][d1], Asrc1 + k0);
    async16(&As[buf][8192 + d0], Asrc0 + hskip + k0);
    async16(&As[buf][8192 + d1], Asrc1 + hskip + k0);
  };
  auto stageB = [&](int buf, int k0) {
    async16(&Bs[buf][d0], Bsrc0 + k0);
    async16(&Bs[buf][d1], Bsrc1 + k0);
    async16(&Bs[buf][8192 + d0], Bsrc0 + hskip + k0);
    async16(&Bs[buf][8192 + d1], Bsrc1 + hskip + k0);
  };

  f32x4 acc[8][4];
#pragma unroll
  for (int i = 0; i < 8; ++i)
#pragma unroll
    for (int j = 0; j < 4; ++j) acc[i][j] = f32x4{0.f, 0.f, 0.f, 0.f};

  const int nt = K / BK;
  stageA(0, 0); stageB(0, 0);
  if (nt > 1) stageB(1, BK);
  asm volatile("s_waitcnt vmcnt(0)" ::: "memory");
  __builtin_amdgcn_s_barrier();

  for (int tt = 0; tt < nt; ++tt) {
    const int buf = tt & 1;
    u16x8 bfr[4][2];
#pragma unroll
    for (int p = 0; p < 2; ++p) {
      if (p == 0) {
#pragma unroll
        for (int j = 0; j < 4; ++j) {
          const int brw = wn * 64 + j * 16 + lr;
#pragma unroll
          for (int s = 0; s < 2; ++s)
            bfr[j][s] = *(const u16x8*)&Bs[buf][brw * 64 + ((((s << 2) + g) ^ l7) << 3)];
        }
      }
      u16x8 af[4][2];
#pragma unroll
      for (int ii = 0; ii < 4; ++ii) {
        const int arow = wm * 128 + (p * 4 + ii) * 16 + lr;
#pragma unroll
        for (int s = 0; s < 2; ++s)
          af[ii][s] = *(const u16x8*)&As[buf][arow * 64 + ((((s << 2) + g) ^ l7) << 3)];
      }
      if (p == 0) {
        if (tt + 1 < nt) stageA(buf ^ 1, (tt + 1) * BK);
      } else {
        if (tt + 2 < nt) {
          stageB(buf, (tt + 2) * BK);
          asm volatile("s_waitcnt vmcnt(4)" ::: "memory");
        } else {
          asm volatile("s_waitcnt vmcnt(0)" ::: "memory");
        }
      }
      __builtin_amdgcn_s_barrier();
      __builtin_amdgcn_s_setprio(1);
#pragma unroll
      for (int ii = 0; ii < 4; ++ii)
#pragma unroll
        for (int j = 0; j < 4; ++j)
#pragma unroll
          for (int s = 0; s < 2; ++s)
            acc[p * 4 + ii][j] = mfma16(af[ii][s], bfr[j][s], acc[p * 4 + ii][j]);
      __builtin_amdgcn_s_setprio(0);
      __builtin_amdgcn_s_barrier();
    }
  }

#pragma unroll
  for (int i = 0; i < 8; ++i) {
#pragma unroll
    for (int j = 0; j < 4; ++j) {
      const int col = bcol + wn * 64 + j * 16 + lr;
      const float bb = bias[col];
#pragma unroll
      for (int r = 0; r < 4; ++r) {
        const int row = brow + wm * 128 + i * 16 + (g << 2) + r;
        outF[(size_t)row * N + col] = acc[i][j][r] + bb;
      }
    }
  }
}

// ------------- flash attention (causal, GQA 4:1), T15 double-pipeline -------
// (round-22 verified: 127.3 us, VGPR 124, no spill)
__global__ __launch_bounds__(512, 1)
void attn_fwd(const uint16_t* __restrict__ Q,   // [B*16][T][128], pre-scaled by QSC
              const uint16_t* __restrict__ Kg,  // [B*4][T][128]
              const uint16_t* __restrict__ Vt,  // [B*4][128][T]
              uint16_t* __restrict__ Y,         // [B*T][2048], col offset h*128
              int T) {
  __shared__ __align__(16) uint16_t Ks[2][64 * 128];   // 32 KB (parity dbuf)
  __shared__ __align__(16) uint16_t Vs[2][128 * 64];   // 32 KB (parity dbuf)
  const int id = (int)blockIdx.x;
  const int x = id & 7;
  const int h = (id >> 3) & 15, b = (id >> 7) & 3;
  const int qb = (id & 256) ? 7 - x : x;      // complementary across bit 8
  const int hkv = h >> 2;

  const int t = threadIdx.x, w = t >> 6, lane = t & 63;
  const int ql = lane & 31, b5 = lane >> 5;
  const int swzK = (ql & 15) << 3;
  const int swzV = (ql & 7) << 3;

  const uint16_t* Qp = Q + ((size_t)(b * 16 + h) * T + qb * 256) * 128;
  const uint16_t* Kp = Kg + (size_t)(b * 4 + hkv) * T * 128;
  const uint16_t* Vp = Vt + (size_t)(b * 4 + hkv) * 128 * T;

  auto stageK = [&](int buf, int kv0) {
#pragma unroll
    for (int l = 0; l < 2; ++l) {
      const int s = l * 512 + t;
      const int row = s >> 4;                       // 0..63
      const int cl = (s & 15) ^ (row & 15);
      async16(&Ks[buf][s * 8], &Kp[(size_t)(kv0 + row) * 128 + cl * 8]);
    }
  };
  auto stageV = [&](int buf, int kv0) {
#pragma unroll
    for (int l = 0; l < 2; ++l) {
      const int s = l * 512 + t;
      const int row = s >> 3;                       // 0..127
      const int cl = (s & 7) ^ (row & 7);
      async16(&Vs[buf][s * 8], &Vp[(size_t)row * T + kv0 + cl * 8]);
    }
  };

  const int row0 = qb * 256 + w * 32;
  const int qrow = row0 + ql;

  u16x8 qf[8];
#pragma unroll
  for (int kc = 0; kc < 8; ++kc)
    qf[kc] = *(const u16x8*)&Qp[(size_t)(w * 32 + ql) * 128 + kc * 16 + b5 * 8];

  f32x16 o[4];  // O^T: lane holds O[d=32db+(reg&3)+8(reg>>2)+4b5][q=ql]
#pragma unroll
  for (int db = 0; db < 4; ++db)
#pragma unroll
    for (int r = 0; r < 16; ++r) o[db][r] = 0.f;
  float mrow = -3e38f, lrow = 0.f;

  const int ntiles = 4 * qb + 4;                 // even
  const int myn = 4 * qb + (w >> 1) + 1;         // waves skip masked tail tiles

  auto qk = [&](int tp, f32x16* sp) {
    sp[0] = 0.f; sp[1] = 0.f;
    const int kbuf = tp & 1;
    __builtin_amdgcn_s_setprio(1);
#pragma unroll
    for (int kc = 0; kc < 8; ++kc) {
      const int cc = (kc * 16 + b5 * 8) ^ swzK;
      u16x8 k0f = *(const u16x8*)&Ks[kbuf][ql * 128 + cc];
      u16x8 k1f = *(const u16x8*)&Ks[kbuf][(32 + ql) * 128 + cc];
      sp[0] = mfma32(k0f, qf[kc], sp[0]);
      sp[1] = mfma32(k1f, qf[kc], sp[1]);
    }
    __builtin_amdgcn_s_setprio(0);
  };

  auto finish = [&](int tp, f32x16* sp) {
    const int kv0 = tp << 6;
    if (kv0 + 63 > row0) {
#pragma unroll
      for (int m = 0; m < 2; ++m)
#pragma unroll
        for (int r = 0; r < 16; ++r) {
          const int kg = kv0 + 32 * m + (r & 3) + 8 * (r >> 2) + 4 * b5;
          if (kg > qrow) sp[m][r] = -3e38f;
        }
    }
    float mt[16];
#pragma unroll
    for (int r = 0; r < 16; ++r) mt[r] = fmaxf(sp[0][r], sp[1][r]);
#pragma unroll
    for (int st = 8; st >= 1; st >>= 1)
#pragma unroll
      for (int r = 0; r < st; ++r) mt[r] = fmaxf(mt[r], mt[r + st]);
    float mx = fmaxf(mt[0], __shfl_xor(mt[0], 32));
    const bool defer = __all(mx <= mrow + 8.f);
    const float mnew = defer ? mrow : fmaxf(mrow, mx);
    const float sc = defer ? 1.f : exp2f(mrow - mnew);
#pragma unroll
    for (int m = 0; m < 2; ++m)
#pragma unroll
      for (int r = 0; r < 16; ++r) sp[m][r] = exp2f(sp[m][r] - mnew);
    float pt[16];
#pragma unroll
    for (int r = 0; r < 16; ++r) pt[r] = sp[0][r] + sp[1][r];
#pragma unroll
    for (int st = 8; st >= 1; st >>= 1)
#pragma unroll
      for (int r = 0; r < st; ++r) pt[r] += pt[r + st];
    float ps = pt[0] + __shfl_xor(pt[0], 32);
    mrow = mnew;
    lrow = lrow * sc + ps;
    if (!defer) {
#pragma unroll
      for (int db = 0; db < 4; ++db)
#pragma unroll
        for (int r = 0; r < 16; ++r) o[db][r] *= sc;
    }
    u16x8 pa[4];
#pragma unroll
    for (int m = 0; m < 2; ++m) {
      uint32_t pw[4][2];
#pragma unroll
      for (int a = 0; a < 4; ++a)
#pragma unroll
        for (int hh = 0; hh < 2; ++hh)
          pw[a][hh] = (uint32_t)f2bfn(sp[m][4 * a + 2 * hh]) |
                      ((uint32_t)f2bfn(sp[m][4 * a + 2 * hh + 1]) << 16);
#pragma unroll
      for (int c = 0; c < 2; ++c) {
        uint32_t wd[4];
#pragma unroll
        for (int hh = 0; hh < 2; ++hh) {
          const uint32_t mine  = b5 ? pw[2 * c + 1][hh] : pw[2 * c][hh];
          const uint32_t yours = b5 ? pw[2 * c][hh] : pw[2 * c + 1][hh];
          const uint32_t xw = (uint32_t)__shfl_xor((int)yours, 32);
          wd[hh] = b5 ? xw : mine;
          wd[2 + hh] = b5 ? mine : xw;
        }
        u32x4 tmp = {wd[0], wd[1], wd[2], wd[3]};
        pa[2 * m + c] = __builtin_bit_cast(u16x8, tmp);
      }
    }
    const int vbuf = tp & 1;
    __builtin_amdgcn_s_setprio(1);
#pragma unroll
    for (int db = 0; db < 4; ++db) {
#pragma unroll
      for (int kf = 0; kf < 4; ++kf) {
        u16x8 vf = *(const u16x8*)&Vs[vbuf][(32 * db + ql) * 64 +
                                           ((kf * 16 + b5 * 8) ^ swzV)];
        o[db] = mfma32(vf, pa[kf], o[db]);
      }
    }
    __builtin_amdgcn_s_setprio(0);
  };

  f32x16 sA[2], sB[2];

  stageK(0, 0);
  __syncthreads();

  for (int tile = 0; tile < ntiles; tile += 2) {
    stageV(0, tile << 6);
    if (tile + 1 < ntiles) stageK(1, (tile + 1) << 6);
    if (tile < myn) qk(tile, sA);
    if (tile >= 1 && tile - 1 < myn) finish(tile - 1, sB);
    __syncthreads();
    const int t2 = tile + 1;
    stageV(1, t2 << 6);
    if (t2 + 1 < ntiles) stageK(0, (t2 + 1) << 6);
    if (t2 < myn) qk(t2, sB);
    if (t2 - 1 < myn) finish(t2 - 1, sA);
    __syncthreads();
  }
  if (ntiles - 1 < myn) finish(ntiles - 1, sB);

  uint16_t* Yp = Y + ((size_t)(b * T + row0 + ql)) * 2048 + h * 128 + b5 * 4;
  const float inv = 1.f / lrow;
#pragma unroll
  for (int db = 0; db < 4; ++db)
#pragma unroll
    for (int a = 0; a < 4; ++a) {
      u16x4v pk;
#pragma unroll
      for (int r = 0; r < 4; ++r) pk[r] = f2bfn(o[db][4 * a + r] * inv);
      *(u16x4v*)&Yp[db * 32 + a * 8] = pk;
    }
}

extern "C" void kernel_launch(void* const* d_in, const int* in_sizes, int n_in,
                              void* d_out, int out_size, void* d_ws, size_t ws_size,
                              hipStream_t stream) {
  const float* x      = (const float*)d_in[0];
  const float* W_attn = (const float*)d_in[1];
  const float* b_attn = (const float*)d_in[2];
  const float* W_proj = (const float*)d_in[3];
  const float* b_proj = (const float*)d_in[4];
  float* out = (float*)d_out;

  const int B = 4, T = 2048, C = 2048, H = 16, HKV = 4, HS = 128;
  const int M = B * T;               // 8192
  const int Nqkv = C + 2 * HKV * HS; // 3072

  uint8_t* ws = (uint8_t*)d_ws;
  size_t off = 0;
  auto alloc = [&](size_t bytes) {
    void* p = ws + off;
    off += (bytes + 255) & ~(size_t)255;
    return p;
  };
  uint16_t* xb  = (uint16_t*)alloc((size_t)M * C * 2);      // reused as yb after qkv
  uint16_t* WaT = (uint16_t*)alloc((size_t)Nqkv * C * 2);
  uint16_t* WpT = (uint16_t*)alloc((size_t)C * C * 2);
  uint16_t* qb  = (uint16_t*)alloc((size_t)B * H * T * HS * 2);
  uint16_t* kb  = (uint16_t*)alloc((size_t)B * HKV * T * HS * 2);
  uint16_t* vtb = (uint16_t*)alloc((size_t)B * HKV * HS * T * 2);  // V^T direct
  uint16_t* yb  = xb;

  cvt_f32_bf16<<<2048, 256, 0, stream>>>(x, xb, M * C / 4);
  transp_cvt<<<dim3(Nqkv / 64, C / 64), 256, 0, stream>>>(W_attn, WaT, C, Nqkv);
  transp_cvt<<<dim3(C / 64, C / 64), 256, 0, stream>>>(W_proj, WpT, C, C);
  gemm_qkv<<<dim3((M / 256) * (Nqkv / 192)), 512, 0, stream>>>(
      xb, WaT, b_attn, qb, kb, vtb, M, Nqkv, C);
  attn_fwd<<<dim3(512), 512, 0, stream>>>(qb, kb, vtb, yb, T);
  gemm_proj<<<dim3((M / 256) * (C / 256)), 512, 0, stream>>>(
      yb, WpT, b_proj, out, M, C, C);
}

// Round 24
// 308.755 us; speedup vs baseline: 1.0178x; 1.0178x over previous
//
#include <hip/hip_runtime.h>
#include <stdint.h>

#define DEVI __device__ __forceinline__

typedef __attribute__((ext_vector_type(8))) uint16_t u16x8;
typedef __attribute__((ext_vector_type(4))) uint16_t u16x4v;
typedef __attribute__((ext_vector_type(4))) uint32_t u32x4;
typedef __attribute__((ext_vector_type(8))) __bf16 bf16x8;
typedef __attribute__((ext_vector_type(4))) float f32x4;
typedef __attribute__((ext_vector_type(16))) float f32x16;

DEVI uint16_t f2bf(float x) {
  union { float f; uint32_t u; } v; v.f = x;
  return (uint16_t)((v.u + 0x7fffu + ((v.u >> 16) & 1u)) >> 16);
}

DEVI uint16_t f2bfn(float f) {
  __bf16 h = (__bf16)f;
  return __builtin_bit_cast(uint16_t, h);
}

DEVI f32x4 mfma16(u16x8 a, u16x8 b, f32x4 c) {
  return __builtin_amdgcn_mfma_f32_16x16x32_bf16(
      __builtin_bit_cast(bf16x8, a), __builtin_bit_cast(bf16x8, b), c, 0, 0, 0);
}

DEVI f32x16 mfma32(u16x8 a, u16x8 b, f32x16 c) {
  return __builtin_amdgcn_mfma_f32_32x32x16_bf16(
      __builtin_bit_cast(bf16x8, a), __builtin_bit_cast(bf16x8, b), c, 0, 0, 0);
}

DEVI void async16(void* lds, const void* g) {
  __builtin_amdgcn_global_load_lds(
      (const __attribute__((address_space(1))) uint32_t*)g,
      (__attribute__((address_space(3))) uint32_t*)lds, 16, 0, 0);
}

// 1/sqrt(128) * log2(e): softmax computed in exp2 domain, scale folded into Q.
#define QSC 0.12751742925f

// ---------------- elementwise f32 -> bf16 ----------------
__global__ void cvt_f32_bf16(const float* __restrict__ in, uint16_t* __restrict__ out, int n4) {
  int i = blockIdx.x * blockDim.x + threadIdx.x;
  const int st = gridDim.x * blockDim.x;
  for (; i < n4; i += st) {
    float4 v = ((const float4*)in)[i];
    u16x4v o;
    o[0] = f2bf(v.x); o[1] = f2bf(v.y); o[2] = f2bf(v.z); o[3] = f2bf(v.w);
    ((u16x4v*)out)[i] = o;
  }
}

// ------------- transpose + convert: f32 [K][N] -> bf16 [N][K] -------------
__global__ void transp_cvt(const float* __restrict__ in, uint16_t* __restrict__ out,
                           int K, int N) {
  __shared__ float Ws[64][65];
  const int n0 = blockIdx.x * 64, k0 = blockIdx.y * 64;
  const int t = threadIdx.x;
  const int r = t >> 4, c = (t & 15) << 2;
#pragma unroll
  for (int it = 0; it < 4; ++it) {
    float4 v = *(const float4*)&in[(size_t)(k0 + it * 16 + r) * N + n0 + c];
    Ws[it * 16 + r][c] = v.x; Ws[it * 16 + r][c + 1] = v.y;
    Ws[it * 16 + r][c + 2] = v.z; Ws[it * 16 + r][c + 3] = v.w;
  }
  __syncthreads();
#pragma unroll
  for (int it = 0; it < 4; ++it) {
    const int rr = it * 16 + r;   // n index in tile
    const int cc = c;             // k index in tile
    ushort4 o;
    o.x = f2bf(Ws[cc][rr]);     o.y = f2bf(Ws[cc + 1][rr]);
    o.z = f2bf(Ws[cc + 2][rr]); o.w = f2bf(Ws[cc + 3][rr]);
    *(ushort4*)&out[(size_t)(n0 + rr) * K + k0 + cc] = o;
  }
}

// ------ qkv GEMM: 256x192 tile, SINGLE-phase x 48-MFMA (round-21/22) ------
__global__ __launch_bounds__(512, 1)
void gemm_qkv(const uint16_t* __restrict__ A, const uint16_t* __restrict__ Bt,
              const float* __restrict__ bias,
              uint16_t* __restrict__ q, uint16_t* __restrict__ kk, uint16_t* __restrict__ vt,
              int M, int N, int K) {
  constexpr int BK = 64;
  __shared__ uint16_t As[2][256 * BK];   // 64 KB
  __shared__ uint16_t Bs[2][192 * BK];   // 48 KB
  int bid = (int)blockIdx.x;
  const int q8 = (int)gridDim.x >> 3;
  bid = (bid & 7) * q8 + (bid >> 3);
  const int nbn = N / 192;
  const int brow = (bid / nbn) << 8;
  const int bcol = (bid % nbn) * 192;
  const int t = threadIdx.x;
  const int wid = t >> 6, lane = t & 63;
  const int wm = wid >> 1, wn = wid & 1;          // 4 x 2 wave grid (64 x 96 per wave)
  const int lr = lane & 15, g = lane >> 4, l7 = lr & 7;

  const int logch = (((t & 7) ^ ((t >> 3) & 7)) << 3);
  const uint16_t* Asrc = A + (size_t)(brow + (t >> 3)) * K + logch;
  const uint16_t* Bsrc = Bt + (size_t)(bcol + (t >> 3)) * K + logch;
  const size_t skip64 = (size_t)64 * K;
  const int dt = t * 8;

  auto stageA = [&](int buf, int k0) {
#pragma unroll
    for (int l = 0; l < 4; ++l)
      async16(&As[buf][l * 4096 + dt], Asrc + (size_t)l * skip64 + k0);
  };
  auto stageB = [&](int buf, int k0) {
#pragma unroll
    for (int l = 0; l < 3; ++l)
      async16(&Bs[buf][l * 4096 + dt], Bsrc + (size_t)l * skip64 + k0);
  };

  f32x4 acc[4][6];
#pragma unroll
  for (int i = 0; i < 4; ++i)
#pragma unroll
    for (int j = 0; j < 6; ++j) acc[i][j] = f32x4{0.f, 0.f, 0.f, 0.f};

  const int nt = K / BK;
  stageA(0, 0); stageB(0, 0);
  if (nt > 1) { stageA(1, BK); stageB(1, BK); }
  asm volatile("s_waitcnt vmcnt(0)" ::: "memory");
  __builtin_amdgcn_s_barrier();

  for (int tt = 0; tt < nt; ++tt) {
    const int buf = tt & 1;
    u16x8 bfr[6][2], af[4][2];
#pragma unroll
    for (int j = 0; j < 6; ++j) {
      const int brw = wn * 96 + j * 16 + lr;
#pragma unroll
      for (int s = 0; s < 2; ++s)
        bfr[j][s] = *(const u16x8*)&Bs[buf][brw * 64 + ((((s << 2) + g) ^ l7) << 3)];
    }
#pragma unroll
    for (int ii = 0; ii < 4; ++ii) {
      const int arow = wm * 64 + ii * 16 + lr;
#pragma unroll
      for (int s = 0; s < 2; ++s)
        af[ii][s] = *(const u16x8*)&As[buf][arow * 64 + ((((s << 2) + g) ^ l7) << 3)];
    }
    asm volatile("s_waitcnt lgkmcnt(0)" ::: "memory");
    __builtin_amdgcn_sched_barrier(0);
    __builtin_amdgcn_s_barrier();          // all waves' reads of buf complete
    if (tt + 2 < nt) {
      stageA(buf, (tt + 2) * BK);          // buf is dead; reuse for t+2
      stageB(buf, (tt + 2) * BK);
      asm volatile("s_waitcnt vmcnt(7)" ::: "memory");  // t+1 proven landed
    } else {
      asm volatile("s_waitcnt vmcnt(0)" ::: "memory");
    }
    __builtin_amdgcn_s_setprio(1);
#pragma unroll
    for (int ii = 0; ii < 4; ++ii)
#pragma unroll
      for (int j = 0; j < 6; ++j)
#pragma unroll
        for (int s = 0; s < 2; ++s)
          acc[ii][j] = mfma16(af[ii][s], bfr[j][s], acc[ii][j]);
    __builtin_amdgcn_s_setprio(0);
    __builtin_amdgcn_s_barrier();          // publish vmcnt guarantee
  }

#pragma unroll
  for (int i = 0; i < 4; ++i) {
#pragma unroll
    for (int j = 0; j < 6; ++j) {
      const int col = bcol + wn * 96 + j * 16 + lr;
      const float bb = bias[col];
      const int rowb = brow + wm * 64 + i * 16 + (g << 2);
      const int b_ = rowb >> 11, ttb = rowb & 2047;   // r-span stays in one seq
      const int d = col & 127;
      float vals[4];
#pragma unroll
      for (int r = 0; r < 4; ++r) vals[r] = acc[i][j][r] + bb;
      if (col < 2048) {
        const int hh = col >> 7;
#pragma unroll
        for (int r = 0; r < 4; ++r)
          q[((size_t)((b_ * 16 + hh) * 2048 + ttb + r) << 7) + d] = f2bf(vals[r] * QSC);
      } else if (col < 2560) {
        const int hh = (col - 2048) >> 7;
#pragma unroll
        for (int r = 0; r < 4; ++r)
          kk[((size_t)((b_ * 4 + hh) * 2048 + ttb + r) << 7) + d] = f2bf(vals[r]);
      } else {
        const int hh = (col - 2560) >> 7;
        u16x4v pk;
#pragma unroll
        for (int r = 0; r < 4; ++r) pk[r] = f2bf(vals[r]);
        *(u16x4v*)&vt[(((size_t)((b_ * 4 + hh) * 128 + d)) << 11) + ttb] = pk;
      }
    }
  }
}

// ------ proj GEMM: 256x256, 2-phase x 32-MFMA (round-20, verified) ------
__global__ __launch_bounds__(512, 1)
void gemm_proj(const uint16_t* __restrict__ A, const uint16_t* __restrict__ Bt,
               const float* __restrict__ bias, float* __restrict__ outF,
               int M, int N, int K) {
  constexpr int BK = 64;
  __shared__ uint16_t As[2][256 * BK];   // 64 KB
  __shared__ uint16_t Bs[2][256 * BK];   // 64 KB
  int bid = (int)blockIdx.x;
  const int q8 = (int)gridDim.x >> 3;
  bid = (bid & 7) * q8 + (bid >> 3);
  const int nbn = N >> 8;
  const int brow = (bid / nbn) << 8;
  const int bcol = (bid % nbn) << 8;
  const int t = threadIdx.x;
  const int wid = t >> 6, lane = t & 63;
  const int wm = wid >> 2, wn = wid & 3;          // 2 x 4 wave grid
  const int lr = lane & 15, g = lane >> 4;
  const int l7 = lr & 7;

  const int sr0 = t >> 3;
  const int logch = (((t & 7) ^ ((t >> 3) & 7)) << 3);
  const uint16_t* Asrc0 = A + (size_t)(brow + sr0) * K + logch;
  const uint16_t* Asrc1 = A + (size_t)(brow + 64 + sr0) * K + logch;
  const uint16_t* Bsrc0 = Bt + (size_t)(bcol + sr0) * K + logch;
  const uint16_t* Bsrc1 = Bt + (size_t)(bcol + 64 + sr0) * K + logch;
  const size_t hskip = (size_t)128 * K;
  const int d0 = t * 8, d1 = 4096 + t * 8;

  auto stageA = [&](int buf, int k0) {
    async16(&As[buf][d0], Asrc0 + k0);
    async16(&As[buf][d1], Asrc1 + k0);
    async16(&As[buf][8192 + d0], Asrc0 + hskip + k0);
    async16(&As[buf][8192 + d1], Asrc1 + hskip + k0);
  };
  auto stageB = [&](int buf, int k0) {
    async16(&Bs[buf][d0], Bsrc0 + k0);
    async16(&Bs[buf][d1], Bsrc1 + k0);
    async16(&Bs[buf][8192 + d0], Bsrc0 + hskip + k0);
    async16(&Bs[buf][8192 + d1], Bsrc1 + hskip + k0);
  };

  f32x4 acc[8][4];
#pragma unroll
  for (int i = 0; i < 8; ++i)
#pragma unroll
    for (int j = 0; j < 4; ++j) acc[i][j] = f32x4{0.f, 0.f, 0.f, 0.f};

  const int nt = K / BK;
  stageA(0, 0); stageB(0, 0);
  if (nt > 1) stageB(1, BK);
  asm volatile("s_waitcnt vmcnt(0)" ::: "memory");
  __builtin_amdgcn_s_barrier();

  for (int tt = 0; tt < nt; ++tt) {
    const int buf = tt & 1;
    u16x8 bfr[4][2];
#pragma unroll
    for (int p = 0; p < 2; ++p) {
      if (p == 0) {
#pragma unroll
        for (int j = 0; j < 4; ++j) {
          const int brw = wn * 64 + j * 16 + lr;
#pragma unroll
          for (int s = 0; s < 2; ++s)
            bfr[j][s] = *(const u16x8*)&Bs[buf][brw * 64 + ((((s << 2) + g) ^ l7) << 3)];
        }
      }
      u16x8 af[4][2];
#pragma unroll
      for (int ii = 0; ii < 4; ++ii) {
        const int arow = wm * 128 + (p * 4 + ii) * 16 + lr;
#pragma unroll
        for (int s = 0; s < 2; ++s)
          af[ii][s] = *(const u16x8*)&As[buf][arow * 64 + ((((s << 2) + g) ^ l7) << 3)];
      }
      if (p == 0) {
        if (tt + 1 < nt) stageA(buf ^ 1, (tt + 1) * BK);
      } else {
        if (tt + 2 < nt) {
          stageB(buf, (tt + 2) * BK);
          asm volatile("s_waitcnt vmcnt(4)" ::: "memory");
        } else {
          asm volatile("s_waitcnt vmcnt(0)" ::: "memory");
        }
      }
      __builtin_amdgcn_s_barrier();
      __builtin_amdgcn_s_setprio(1);
#pragma unroll
      for (int ii = 0; ii < 4; ++ii)
#pragma unroll
        for (int j = 0; j < 4; ++j)
#pragma unroll
          for (int s = 0; s < 2; ++s)
            acc[p * 4 + ii][j] = mfma16(af[ii][s], bfr[j][s], acc[p * 4 + ii][j]);
      __builtin_amdgcn_s_setprio(0);
      __builtin_amdgcn_s_barrier();
    }
  }

#pragma unroll
  for (int i = 0; i < 8; ++i) {
#pragma unroll
    for (int j = 0; j < 4; ++j) {
      const int col = bcol + wn * 64 + j * 16 + lr;
      const float bb = bias[col];
#pragma unroll
      for (int r = 0; r < 4; ++r) {
        const int row = brow + wm * 128 + i * 16 + (g << 2) + r;
        outF[(size_t)row * N + col] = acc[i][j][r] + bb;
      }
    }
  }
}

// ------------- flash attention (causal, GQA 4:1), T15 double-pipeline -------
// (round-22 verified: 127.3 us, VGPR 124, no spill)
__global__ __launch_bounds__(512, 1)
void attn_fwd(const uint16_t* __restrict__ Q,   // [B*16][T][128], pre-scaled by QSC
              const uint16_t* __restrict__ Kg,  // [B*4][T][128]
              const uint16_t* __restrict__ Vt,  // [B*4][128][T]
              uint16_t* __restrict__ Y,         // [B*T][2048], col offset h*128
              int T) {
  __shared__ __align__(16) uint16_t Ks[2][64 * 128];   // 32 KB (parity dbuf)
  __shared__ __align__(16) uint16_t Vs[2][128 * 64];   // 32 KB (parity dbuf)
  const int id = (int)blockIdx.x;
  const int x = id & 7;
  const int h = (id >> 3) & 15, b = (id >> 7) & 3;
  const int qb = (id & 256) ? 7 - x : x;      // complementary across bit 8
  const int hkv = h >> 2;

  const int t = threadIdx.x, w = t >> 6, lane = t & 63;
  const int ql = lane & 31, b5 = lane >> 5;
  const int swzK = (ql & 15) << 3;
  const int swzV = (ql & 7) << 3;

  const uint16_t* Qp = Q + ((size_t)(b * 16 + h) * T + qb * 256) * 128;
  const uint16_t* Kp = Kg + (size_t)(b * 4 + hkv) * T * 128;
  const uint16_t* Vp = Vt + (size_t)(b * 4 + hkv) * 128 * T;

  auto stageK = [&](int buf, int kv0) {
#pragma unroll
    for (int l = 0; l < 2; ++l) {
      const int s = l * 512 + t;
      const int row = s >> 4;                       // 0..63
      const int cl = (s & 15) ^ (row & 15);
      async16(&Ks[buf][s * 8], &Kp[(size_t)(kv0 + row) * 128 + cl * 8]);
    }
  };
  auto stageV = [&](int buf, int kv0) {
#pragma unroll
    for (int l = 0; l < 2; ++l) {
      const int s = l * 512 + t;
      const int row = s >> 3;                       // 0..127
      const int cl = (s & 7) ^ (row & 7);
      async16(&Vs[buf][s * 8], &Vp[(size_t)row * T + kv0 + cl * 8]);
    }
  };

  const int row0 = qb * 256 + w * 32;
  const int qrow = row0 + ql;

  u16x8 qf[8];
#pragma unroll
  for (int kc = 0; kc < 8; ++kc)
    qf[kc] = *(const u16x8*)&Qp[(size_t)(w * 32 + ql) * 128 + kc * 16 + b5 * 8];

  f32x16 o[4];  // O^T: lane holds O[d=32db+(reg&3)+8(reg>>2)+4b5][q=ql]
#pragma unroll
  for (int db = 0; db < 4; ++db)
#pragma unroll
    for (int r = 0; r < 16; ++r) o[db][r] = 0.f;
  float mrow = -3e38f, lrow = 0.f;

  const int ntiles = 4 * qb + 4;                 // even
  const int myn = 4 * qb + (w >> 1) + 1;         // waves skip masked tail tiles

  auto qk = [&](int tp, f32x16* sp) {
    sp[0] = 0.f; sp[1] = 0.f;
    const int kbuf = tp & 1;
    __builtin_amdgcn_s_setprio(1);
#pragma unroll
    for (int kc = 0; kc < 8; ++kc) {
      const int cc = (kc * 16 + b5 * 8) ^ swzK;
      u16x8 k0f = *(const u16x8*)&Ks[kbuf][ql * 128 + cc];
      u16x8 k1f = *(const u16x8*)&Ks[kbuf][(32 + ql) * 128 + cc];
      sp[0] = mfma32(k0f, qf[kc], sp[0]);
      sp[1] = mfma32(k1f, qf[kc], sp[1]);
    }
    __builtin_amdgcn_s_setprio(0);
  };

  auto finish = [&](int tp, f32x16* sp) {
    const int kv0 = tp << 6;
    if (kv0 + 63 > row0) {
#pragma unroll
      for (int m = 0; m < 2; ++m)
#pragma unroll
        for (int r = 0; r < 16; ++r) {
          const int kg = kv0 + 32 * m + (r & 3) + 8 * (r >> 2) + 4 * b5;
          if (kg > qrow) sp[m][r] = -3e38f;
        }
    }
    float mt[16];
#pragma unroll
    for (int r = 0; r < 16; ++r) mt[r] = fmaxf(sp[0][r], sp[1][r]);
#pragma unroll
    for (int st = 8; st >= 1; st >>= 1)
#pragma unroll
      for (int r = 0; r < st; ++r) mt[r] = fmaxf(mt[r], mt[r + st]);
    float mx = fmaxf(mt[0], __shfl_xor(mt[0], 32));
    const bool defer = __all(mx <= mrow + 8.f);
    const float mnew = defer ? mrow : fmaxf(mrow, mx);
    const float sc = defer ? 1.f : exp2f(mrow - mnew);
#pragma unroll
    for (int m = 0; m < 2; ++m)
#pragma unroll
      for (int r = 0; r < 16; ++r) sp[m][r] = exp2f(sp[m][r] - mnew);
    float pt[16];
#pragma unroll
    for (int r = 0; r < 16; ++r) pt[r] = sp[0][r] + sp[1][r];
#pragma unroll
    for (int st = 8; st >= 1; st >>= 1)
#pragma unroll
      for (int r = 0; r < st; ++r) pt[r] += pt[r + st];
    float ps = pt[0] + __shfl_xor(pt[0], 32);
    mrow = mnew;
    lrow = lrow * sc + ps;
    if (!defer) {
#pragma unroll
      for (int db = 0; db < 4; ++db)
#pragma unroll
        for (int r = 0; r < 16; ++r) o[db][r] *= sc;
    }
    u16x8 pa[4];
#pragma unroll
    for (int m = 0; m < 2; ++m) {
      uint32_t pw[4][2];
#pragma unroll
      for (int a = 0; a < 4; ++a)
#pragma unroll
        for (int hh = 0; hh < 2; ++hh)
          pw[a][hh] = (uint32_t)f2bfn(sp[m][4 * a + 2 * hh]) |
                      ((uint32_t)f2bfn(sp[m][4 * a + 2 * hh + 1]) << 16);
#pragma unroll
      for (int c = 0; c < 2; ++c) {
        uint32_t wd[4];
#pragma unroll
        for (int hh = 0; hh < 2; ++hh) {
          const uint32_t mine  = b5 ? pw[2 * c + 1][hh] : pw[2 * c][hh];
          const uint32_t yours = b5 ? pw[2 * c][hh] : pw[2 * c + 1][hh];
          const uint32_t xw = (uint32_t)__shfl_xor((int)yours, 32);
          wd[hh] = b5 ? xw : mine;
          wd[2 + hh] = b5 ? mine : xw;
        }
        u32x4 tmp = {wd[0], wd[1], wd[2], wd[3]};
        pa[2 * m + c] = __builtin_bit_cast(u16x8, tmp);
      }
    }
    const int vbuf = tp & 1;
    __builtin_amdgcn_s_setprio(1);
#pragma unroll
    for (int db = 0; db < 4; ++db) {
#pragma unroll
      for (int kf = 0; kf < 4; ++kf) {
        u16x8 vf = *(const u16x8*)&Vs[vbuf][(32 * db + ql) * 64 +
                                           ((kf * 16 + b5 * 8) ^ swzV)];
        o[db] = mfma32(vf, pa[kf], o[db]);
      }
    }
    __builtin_amdgcn_s_setprio(0);
  };

  f32x16 sA[2], sB[2];

  stageK(0, 0);
  __syncthreads();

  for (int tile = 0; tile < ntiles; tile += 2) {
    stageV(0, tile << 6);
    if (tile + 1 < ntiles) stageK(1, (tile + 1) << 6);
    if (tile < myn) qk(tile, sA);
    if (tile >= 1 && tile - 1 < myn) finish(tile - 1, sB);
    __syncthreads();
    const int t2 = tile + 1;
    stageV(1, t2 << 6);
    if (t2 + 1 < ntiles) stageK(0, (t2 + 1) << 6);
    if (t2 < myn) qk(t2, sB);
    if (t2 - 1 < myn) finish(t2 - 1, sA);
    __syncthreads();
  }
  if (ntiles - 1 < myn) finish(ntiles - 1, sB);

  uint16_t* Yp = Y + ((size_t)(b * T + row0 + ql)) * 2048 + h * 128 + b5 * 4;
  const float inv = 1.f / lrow;
#pragma unroll
  for (int db = 0; db < 4; ++db)
#pragma unroll
    for (int a = 0; a < 4; ++a) {
      u16x4v pk;
#pragma unroll
      for (int r = 0; r < 4; ++r) pk[r] = f2bfn(o[db][4 * a + r] * inv);
      *(u16x4v*)&Yp[db * 32 + a * 8] = pk;
    }
}

extern "C" void kernel_launch(void* const* d_in, const int* in_sizes, int n_in,
                              void* d_out, int out_size, void* d_ws, size_t ws_size,
                              hipStream_t stream) {
  const float* x      = (const float*)d_in[0];
  const float* W_attn = (const float*)d_in[1];
  const float* b_attn = (const float*)d_in[2];
  const float* W_proj = (const float*)d_in[3];
  const float* b_proj = (const float*)d_in[4];
  float* out = (float*)d_out;

  const int B = 4, T = 2048, C = 2048, H = 16, HKV = 4, HS = 128;
  const int M = B * T;               // 8192
  const int Nqkv = C + 2 * HKV * HS; // 3072

  uint8_t* ws = (uint8_t*)d_ws;
  size_t off = 0;
  auto alloc = [&](size_t bytes) {
    void* p = ws + off;
    off += (bytes + 255) & ~(size_t)255;
    return p;
  };
  uint16_t* xb  = (uint16_t*)alloc((size_t)M * C * 2);      // reused as yb after qkv
  uint16_t* WaT = (uint16_t*)alloc((size_t)Nqkv * C * 2);
  uint16_t* WpT = (uint16_t*)alloc((size_t)C * C * 2);
  uint16_t* qb  = (uint16_t*)alloc((size_t)B * H * T * HS * 2);
  uint16_t* kb  = (uint16_t*)alloc((size_t)B * HKV * T * HS * 2);
  uint16_t* vtb = (uint16_t*)alloc((size_t)B * HKV * HS * T * 2);  // V^T direct
  uint16_t* yb  = xb;

  cvt_f32_bf16<<<2048, 256, 0, stream>>>(x, xb, M * C / 4);
  transp_cvt<<<dim3(Nqkv / 64, C / 64), 256, 0, stream>>>(W_attn, WaT, C, Nqkv);
  transp_cvt<<<dim3(C / 64, C / 64), 256, 0, stream>>>(W_proj, WpT, C, C);
  gemm_qkv<<<dim3((M / 256) * (Nqkv / 192)), 512, 0, stream>>>(
      xb, WaT, b_attn, qb, kb, vtb, M, Nqkv, C);
  attn_fwd<<<dim3(512), 512, 0, stream>>>(qb, kb, vtb, yb, T);
  gemm_proj<<<dim3((M / 256) * (C / 256)), 512, 0, stream>>>(
      yb, WpT, b_proj, out, M, C, C);
}